// Round 1
// baseline (11981.353 us; speedup 1.0000x reference)
//
#include <hip/hip_runtime.h>

typedef _Float16 h16;
typedef __attribute__((ext_vector_type(8))) _Float16 f16x8;
typedef __attribute__((ext_vector_type(4))) float f32x4;

#define B_ 128
#define T_ 256
#define H_ 512
#define S_ 32

__device__ __forceinline__ float fexp2(float x){ return __builtin_amdgcn_exp2f(x); }
__device__ __forceinline__ float frcp (float x){ return __builtin_amdgcn_rcpf(x); }
__device__ __forceinline__ float fsig (float x){ return frcp(1.f + fexp2(-1.44269504089f*x)); }
__device__ __forceinline__ float ftanh(float x){ return 1.f - 2.f*frcp(1.f + fexp2(2.88539008178f*x)); }

// ---------------------------------------------------------------------------
// Generic fused LSTM step: G = X@Wih^T + Hp@Whh^T + b ; gates ; update C, Hn.
// Block = 4 waves. Block owns (16 batch rows) x (16 hidden units); wave w
// computes gate-w tile (rows w*512 + j0 .. +16). grid.x = 8 m-tiles * 32 j-tiles.
// MFMA 16x16x32 f16: A-frag lane l: A[l&15][(l>>4)*8 + j] (8 consecutive k);
// B-frag lane l: B[k][l&15] = W[l&15-th row][k..] ; C/D: col=lane&15, row=(lane>>4)*4+reg.
// ---------------------------------------------------------------------------
struct StepArgs {
  const h16* X;  int sx; int Kx;   // input (B,Kx), row stride sx (Kx % 32 == 0)
  const h16* Wih;                  // (2048, Kx) row-major
  const h16* Hp; int sh;           // prev hidden (B,512)
  const h16* Whh;                  // (2048, 512)
  const float* bias;               // (2048)
  float* C;                        // cell state (B,512) f32, stride 512 (in/out)
  h16* Hn; int shn;                // new hidden out
};

__global__ __launch_bounds__(256) void lstm_step(StepArgs a0, StepArgs a1) {
  StepArgs A = (blockIdx.y == 0) ? a0 : a1;
  const int m0   = (blockIdx.x >> 5) << 4;
  const int j0   = (blockIdx.x & 31) << 4;
  const int wid  = threadIdx.x >> 6;
  const int lane = threadIdx.x & 63;
  const int r = lane & 15, g = lane >> 4;
  const int n0 = wid * H_ + j0;

  f32x4 acc = {0.f, 0.f, 0.f, 0.f};
  {
    const h16* xp = A.X   + (size_t)(m0 + r) * A.sx + g * 8;
    const h16* wp = A.Wih + (size_t)(n0 + r) * A.Kx + g * 8;
    for (int k = 0; k < A.Kx; k += 32) {
      f16x8 av = *(const f16x8*)(xp + k);
      f16x8 bv = *(const f16x8*)(wp + k);
      acc = __builtin_amdgcn_mfma_f32_16x16x32_f16(av, bv, acc, 0, 0, 0);
    }
  }
  {
    const h16* hp = A.Hp  + (size_t)(m0 + r) * A.sh + g * 8;
    const h16* wp = A.Whh + (size_t)(n0 + r) * H_   + g * 8;
    #pragma unroll
    for (int k = 0; k < H_; k += 32) {
      f16x8 av = *(const f16x8*)(hp + k);
      f16x8 bv = *(const f16x8*)(wp + k);
      acc = __builtin_amdgcn_mfma_f32_16x16x32_f16(av, bv, acc, 0, 0, 0);
    }
  }
  __shared__ float gt[4][16][16];
  #pragma unroll
  for (int t = 0; t < 4; ++t) gt[wid][g * 4 + t][r] = acc[t];
  __syncthreads();

  const int mi = threadIdx.x >> 4, ji = threadIdx.x & 15;
  const int jj = j0 + ji;
  float iv = gt[0][mi][ji] + A.bias[jj];
  float fv = gt[1][mi][ji] + A.bias[H_ + jj];
  float gv = gt[2][mi][ji] + A.bias[2 * H_ + jj];
  float ov = gt[3][mi][ji] + A.bias[3 * H_ + jj];
  float* cp = A.C + (size_t)(m0 + mi) * H_ + jj;
  float c = fsig(fv) * *cp + fsig(iv) * ftanh(gv);
  *cp = c;
  A.Hn[(size_t)(m0 + mi) * A.shn + jj] = (h16)(fsig(ov) * ftanh(c));
}

// ---------------------------------------------------------------------------
// Generic TN GEMM: C[m,n] = act(sum_k A[m,k]*B[n,k] + bias[n])
// A (M,K) f16 row stride lda; B (N,K) f16 row-major (ldb=K).
// mode 0: f32 out; 1: f16 out; 2: tanh -> f16 out.
// grid = (M/64, N/64); wave = one 16-row m-tile x 4 n-tiles.
// ---------------------------------------------------------------------------
__global__ __launch_bounds__(256) void gemm_tn(const h16* Am, int lda, const h16* Bm,
                                               const float* bias, void* Cout, int ldc,
                                               int K, int mode) {
  const int wid = threadIdx.x >> 6, lane = threadIdx.x & 63;
  const int r = lane & 15, g = lane >> 4;
  const int m0 = (blockIdx.x * 4 + wid) * 16;
  const int n0 = blockIdx.y * 64;
  f32x4 acc[4] = {{0,0,0,0},{0,0,0,0},{0,0,0,0},{0,0,0,0}};
  const h16* ap = Am + (size_t)(m0 + r) * lda + g * 8;
  const h16* bp = Bm + (size_t)(n0 + r) * K + g * 8;
  for (int k = 0; k < K; k += 32) {
    f16x8 av = *(const f16x8*)(ap + k);
    #pragma unroll
    for (int j = 0; j < 4; ++j) {
      f16x8 bv = *(const f16x8*)(bp + (size_t)j * 16 * K + k);
      acc[j] = __builtin_amdgcn_mfma_f32_16x16x32_f16(av, bv, acc[j], 0, 0, 0);
    }
  }
  #pragma unroll
  for (int j = 0; j < 4; ++j) {
    const int n = n0 + j * 16 + r;
    const float badd = bias ? bias[n] : 0.f;
    #pragma unroll
    for (int t = 0; t < 4; ++t) {
      const int m = m0 + g * 4 + t;
      float v = acc[j][t] + badd;
      if (mode == 2) v = ftanh(v);
      if (mode == 0) ((float*)Cout)[(size_t)m * ldc + n] = v;
      else           ((h16*)Cout) [(size_t)m * ldc + n] = (h16)v;
    }
  }
}

// ---------------------------------------------------------------------------
// score[m,t] = sum_a tanh(Wa_vals[m,t,a] + qUa[m,a]) * Va[a]   (a < 512)
// one wave per (m,t); grid = B*T/4 blocks of 4 waves.
// ---------------------------------------------------------------------------
__global__ __launch_bounds__(256) void attn_score(const h16* __restrict__ Wv,
                                                  const float* __restrict__ qUa,
                                                  const float* __restrict__ Va,
                                                  float* __restrict__ score) {
  const int wid = threadIdx.x >> 6, lane = threadIdx.x & 63;
  const int wv = blockIdx.x * 4 + wid;
  const int m = wv >> 8, t = wv & 255;
  const h16*  wrow = Wv + (size_t)(m * 256 + t) * 512;
  const float* qrow = qUa + m * 512;
  float s = 0.f;
  #pragma unroll
  for (int i = 0; i < 8; ++i) {
    const int a = i * 64 + lane;
    s += ftanh((float)wrow[a] + qrow[a]) * Va[a];
  }
  #pragma unroll
  for (int o = 32; o; o >>= 1) s += __shfl_xor(s, o);
  if (lane == 0) score[m * 256 + t] = s;
}

// ---------------------------------------------------------------------------
// per-m softmax over T=256 + context z = wts @ enc_out, written as f16 into
// xcat[m][2 .. 1026). One block per m.
// ---------------------------------------------------------------------------
__global__ __launch_bounds__(256) void attn_ctx(const float* __restrict__ score,
                                                const h16* __restrict__ enc,
                                                h16* __restrict__ xcat) {
  const int m = blockIdx.x, tid = threadIdx.x;
  __shared__ float red[256];
  __shared__ float wts[256];
  const float s = score[m * 256 + tid];
  red[tid] = s; __syncthreads();
  for (int o = 128; o; o >>= 1) { if (tid < o) red[tid] = fmaxf(red[tid], red[tid + o]); __syncthreads(); }
  const float mx = red[0]; __syncthreads();
  const float p = fexp2((s - mx) * 1.44269504089f);
  red[tid] = p; __syncthreads();
  for (int o = 128; o; o >>= 1) { if (tid < o) red[tid] += red[tid + o]; __syncthreads(); }
  wts[tid] = p * frcp(red[0]);
  __syncthreads();
  const h16* erow = enc + (size_t)m * 256 * 1024;
  #pragma unroll
  for (int i = 0; i < 4; ++i) {
    const int k = i * 256 + tid;
    float a0 = 0, a1 = 0, a2 = 0, a3 = 0;
    for (int t = 0; t < 256; t += 4) {
      a0 += wts[t    ] * (float)erow[(t    ) * 1024 + k];
      a1 += wts[t + 1] * (float)erow[(t + 1) * 1024 + k];
      a2 += wts[t + 2] * (float)erow[(t + 2) * 1024 + k];
      a3 += wts[t + 3] * (float)erow[(t + 3) * 1024 + k];
    }
    xcat[(size_t)m * 1056 + 2 + k] = (h16)((a0 + a1) + (a2 + a3));
  }
}

// ---------------------------------------------------------------------------
// yn = h1 @ fc_W^T + fc_b  -> d_out column s (f32) and xcat[:,0:2] (f16).
// 16 blocks x 4 waves; wave handles 4 of the 256 (m,o) outputs.
// ---------------------------------------------------------------------------
__global__ __launch_bounds__(256) void fc_out(const h16* __restrict__ h1,
                                              const float* __restrict__ fcW,
                                              const float* __restrict__ fcb,
                                              float* __restrict__ outcol,
                                              h16* __restrict__ xcat) {
  const int wid = threadIdx.x >> 6, lane = threadIdx.x & 63;
  const int wv = blockIdx.x * 4 + wid;
  #pragma unroll
  for (int j = 0; j < 4; ++j) {
    const int idx = wv * 4 + j;
    const int m = idx >> 1, o = idx & 1;
    float s = 0.f;
    #pragma unroll
    for (int i = 0; i < 8; ++i) {
      const int k = i * 64 + lane;
      s += (float)h1[m * 512 + k] * fcW[o * 512 + k];
    }
    #pragma unroll
    for (int off = 32; off; off >>= 1) s += __shfl_xor(s, off);
    if (lane == 0) {
      const float y = s + fcb[o];
      outcol[m * (S_ * 2) + o] = y;      // d_out is (B, S, 2); outcol = d_out + s*2
      xcat[(size_t)m * 1056 + o] = (h16)y;
    }
  }
}

// f32 -> f16 convert with optional K padding (pad columns = 0).
__global__ void convert_pad(const float* __restrict__ in, h16* __restrict__ out,
                            int rows, int Kin, int Kout) {
  const size_t i = (size_t)blockIdx.x * 256 + threadIdx.x;
  if (i >= (size_t)rows * Kout) return;
  const int r = (int)(i / Kout), k = (int)(i % Kout);
  out[i] = (k < Kin) ? (h16)in[(size_t)r * Kin + k] : (h16)0.f;
}

// y0 = x[:, T-1, :2] into xcat[:, 0:2]
__global__ void y0_init(const float* __restrict__ x, h16* __restrict__ xcat) {
  const int tid = threadIdx.x;
  if (tid < 256) {
    const int m = tid >> 1, o = tid & 1;
    xcat[(size_t)m * 1056 + o] = (h16)x[(size_t)(m * T_ + (T_ - 1)) * 8 + o];
  }
}

extern "C" void kernel_launch(void* const* d_in, const int* in_sizes, int n_in,
                              void* d_out, int out_size, void* d_ws, size_t ws_size,
                              hipStream_t stream) {
  const float* x     = (const float*)d_in[0];
  const float* eWih0 = (const float*)d_in[1];
  const float* eWhh0 = (const float*)d_in[2];
  const float* eb0   = (const float*)d_in[3];
  const float* eWih1 = (const float*)d_in[4];
  const float* eWhh1 = (const float*)d_in[5];
  const float* eb1   = (const float*)d_in[6];
  const float* dWih0 = (const float*)d_in[7];
  const float* dWhh0 = (const float*)d_in[8];
  const float* db0   = (const float*)d_in[9];
  const float* dWih1 = (const float*)d_in[10];
  const float* dWhh1 = (const float*)d_in[11];
  const float* db1   = (const float*)d_in[12];
  const float* Wa    = (const float*)d_in[13];
  const float* Ua    = (const float*)d_in[14];
  const float* Va    = (const float*)d_in[15];
  const float* projW = (const float*)d_in[16];
  const float* projb = (const float*)d_in[17];
  const float* fcW   = (const float*)d_in[18];
  const float* fcb   = (const float*)d_in[19];
  float* out = (float*)d_out;

  size_t cur = 0;
  auto alloc = [&](size_t bytes) {
    void* p = (char*)d_ws + cur;
    cur += (bytes + 255) & ~(size_t)255;
    return p;
  };
  h16*  zero   = (h16*) alloc((size_t)B_ * H_ * 2);
  h16*  xpad   = (h16*) alloc((size_t)B_ * T_ * 32 * 2);
  h16*  l1in   = (h16*) alloc((size_t)T_ * B_ * 1024 * 2);   // layer-0 h history (T,B,2H)
  h16*  encout = (h16*) alloc((size_t)B_ * T_ * 1024 * 2);   // layer-1 h history (B,T,2H)
  h16*  WaV    = (h16*) alloc((size_t)B_ * T_ * H_ * 2);
  float* cbuf  = (float*)alloc((size_t)4 * B_ * H_ * 4);     // c0[2], c1[2] contiguous
  float* c0 = cbuf;                // layer-0 cells (dir0, dir1) -> become decoder cells
  float* c1 = cbuf + 2 * B_ * H_;  // layer-1 cells
  float* score = (float*)alloc((size_t)B_ * T_ * 4);
  float* qUa   = (float*)alloc((size_t)B_ * H_ * 4);
  h16*  xcat   = (h16*) alloc((size_t)B_ * 1056 * 2);
  h16*  dh0    = (h16*) alloc((size_t)2 * B_ * H_ * 2);      // decoder h0 ping-pong
  h16*  dh1    = (h16*) alloc((size_t)2 * B_ * H_ * 2);      // decoder h1 ping-pong
  h16*  bWih0  = (h16*) alloc((size_t)2 * 2048 * 32 * 2);
  h16*  bWhh0  = (h16*) alloc((size_t)2 * 2048 * 512 * 2);
  h16*  bWih1  = (h16*) alloc((size_t)2 * 2048 * 1024 * 2);
  h16*  bWhh1  = (h16*) alloc((size_t)2 * 2048 * 512 * 2);
  h16*  bdWih0 = (h16*) alloc((size_t)2048 * 1056 * 2);
  h16*  bdWhh0 = (h16*) alloc((size_t)2048 * 512 * 2);
  h16*  bdWih1 = (h16*) alloc((size_t)2048 * 512 * 2);
  h16*  bdWhh1 = (h16*) alloc((size_t)2048 * 512 * 2);
  h16*  bWa    = (h16*) alloc((size_t)512 * 1024 * 2);
  h16*  bUa    = (h16*) alloc((size_t)512 * 512 * 2);
  h16*  bprojW = (h16*) alloc((size_t)512 * 512 * 2);
  if (cur > ws_size) return;  // workspace too small: fail visibly, no OOB writes

  hipMemsetAsync(zero, 0, (size_t)B_ * H_ * 2, stream);
  hipMemsetAsync(cbuf, 0, (size_t)4 * B_ * H_ * 4, stream);
  hipMemsetAsync(xcat, 0, (size_t)B_ * 1056 * 2, stream);

  auto conv = [&](const float* in, h16* o, int rows, int kin, int kout) {
    const size_t total = (size_t)rows * kout;
    convert_pad<<<dim3((unsigned)((total + 255) / 256)), dim3(256), 0, stream>>>(in, o, rows, kin, kout);
  };
  conv(x,     xpad,   B_ * T_,  8,    32);
  conv(eWih0, bWih0,  2 * 2048, 8,    32);
  conv(eWhh0, bWhh0,  2 * 2048, 512,  512);
  conv(eWih1, bWih1,  2 * 2048, 1024, 1024);
  conv(eWhh1, bWhh1,  2 * 2048, 512,  512);
  conv(dWih0, bdWih0, 2048,     1026, 1056);
  conv(dWhh0, bdWhh0, 2048,     512,  512);
  conv(dWih1, bdWih1, 2048,     512,  512);
  conv(dWhh1, bdWhh1, 2048,     512,  512);
  conv(Wa,    bWa,    512,      1024, 1024);
  conv(Ua,    bUa,    512,      512,  512);
  conv(projW, bprojW, 512,      512,  512);

  // ---- encoder layer 0 (both directions per launch) ----
  for (int i = 0; i < T_; ++i) {
    const int tf = i, tb = T_ - 1 - i;
    StepArgs f{}, b{};
    f.X = xpad + tf * 32;  f.sx = T_ * 32;  f.Kx = 32;
    f.Wih = bWih0;
    f.Hp = i ? l1in + (size_t)(tf - 1) * B_ * 1024 : zero;  f.sh = i ? 1024 : H_;
    f.Whh = bWhh0;  f.bias = eb0;  f.C = c0;
    f.Hn = l1in + (size_t)tf * B_ * 1024;  f.shn = 1024;
    b.X = xpad + tb * 32;  b.sx = T_ * 32;  b.Kx = 32;
    b.Wih = bWih0 + 2048 * 32;
    b.Hp = i ? l1in + (size_t)(tb + 1) * B_ * 1024 + 512 : zero;  b.sh = i ? 1024 : H_;
    b.Whh = bWhh0 + (size_t)2048 * 512;  b.bias = eb0 + 2048;  b.C = c0 + B_ * H_;
    b.Hn = l1in + (size_t)tb * B_ * 1024 + 512;  b.shn = 1024;
    lstm_step<<<dim3(256, 2), dim3(256), 0, stream>>>(f, b);
  }
  // ---- encoder layer 1 ----
  for (int i = 0; i < T_; ++i) {
    const int tf = i, tb = T_ - 1 - i;
    StepArgs f{}, b{};
    f.X = l1in + (size_t)tf * B_ * 1024;  f.sx = 1024;  f.Kx = 1024;
    f.Wih = bWih1;
    f.Hp = i ? encout + (size_t)(tf - 1) * 1024 : zero;  f.sh = i ? T_ * 1024 : H_;
    f.Whh = bWhh1;  f.bias = eb1;  f.C = c1;
    f.Hn = encout + (size_t)tf * 1024;  f.shn = T_ * 1024;
    b.X = l1in + (size_t)tb * B_ * 1024;  b.sx = 1024;  b.Kx = 1024;
    b.Wih = bWih1 + (size_t)2048 * 1024;
    b.Hp = i ? encout + (size_t)(tb + 1) * 1024 + 512 : zero;  b.sh = i ? T_ * 1024 : H_;
    b.Whh = bWhh1 + (size_t)2048 * 512;  b.bias = eb1 + 2048;  b.C = c1 + B_ * H_;
    b.Hn = encout + (size_t)tb * 1024 + 512;  b.shn = T_ * 1024;
    lstm_step<<<dim3(256, 2), dim3(256), 0, stream>>>(f, b);
  }

  // ---- Wa_vals = enc_out @ Wa^T  (f16 out) ----
  gemm_tn<<<dim3(B_ * T_ / 64, 8), dim3(256), 0, stream>>>(encout, 1024, bWa, nullptr, WaV, 512, 1024, 1);
  // ---- decoder h init: dh[d] = tanh(layer0-final-h[d] @ projW^T + projb) ----
  gemm_tn<<<dim3(B_ / 64, 8), dim3(256), 0, stream>>>(l1in + (size_t)(T_ - 1) * B_ * 1024, 1024,
                                                      bprojW, projb, dh0, 512, 512, 2);
  gemm_tn<<<dim3(B_ / 64, 8), dim3(256), 0, stream>>>(l1in + 512, 1024,
                                                      bprojW, projb, dh1, 512, 512, 2);
  y0_init<<<dim3(1), dim3(256), 0, stream>>>(x, xcat);

  // decoder cell states alias the layer-0 final cells (cf0 -> cell0, cb0 -> cell1)
  float* dc0 = c0;
  float* dc1 = c0 + B_ * H_;

  int pp = 0;
  for (int s = 0; s < S_; ++s) {
    const int nx = pp ^ 1;
    h16* h0c = dh0 + (size_t)pp * B_ * H_;  h16* h0n = dh0 + (size_t)nx * B_ * H_;
    h16* h1c = dh1 + (size_t)pp * B_ * H_;  h16* h1n = dh1 + (size_t)nx * B_ * H_;

    gemm_tn<<<dim3(2, 8), dim3(256), 0, stream>>>(h1c, 512, bUa, nullptr, qUa, 512, 512, 0);
    attn_score<<<dim3(B_ * T_ / 4), dim3(256), 0, stream>>>(WaV, qUa, Va, score);
    attn_ctx<<<dim3(B_), dim3(256), 0, stream>>>(score, encout, xcat);

    StepArgs a{};
    a.X = xcat;  a.sx = 1056;  a.Kx = 1056;  a.Wih = bdWih0;
    a.Hp = h0c;  a.sh = 512;   a.Whh = bdWhh0;  a.bias = db0;
    a.C = dc0;   a.Hn = h0n;   a.shn = 512;
    lstm_step<<<dim3(256, 1), dim3(256), 0, stream>>>(a, a);

    StepArgs a2{};
    a2.X = h0n;  a2.sx = 512;  a2.Kx = 512;  a2.Wih = bdWih1;
    a2.Hp = h1c; a2.sh = 512;  a2.Whh = bdWhh1;  a2.bias = db1;
    a2.C = dc1;  a2.Hn = h1n;  a2.shn = 512;
    lstm_step<<<dim3(256, 1), dim3(256), 0, stream>>>(a2, a2);

    fc_out<<<dim3(16), dim3(256), 0, stream>>>(h1n, fcW, fcb, out + s * 2, xcat);
    pp = nx;
  }
}